// Round 1
// baseline (4353.772 us; speedup 1.0000x reference)
//
#include <hip/hip_runtime.h>
#include <hip/hip_bf16.h>
#include <math.h>

typedef float f32x4 __attribute__((ext_vector_type(4)));
typedef __bf16 bf16x8 __attribute__((ext_vector_type(8)));

#define EPI_PATCH  0
#define EPI_QKV    1
#define EPI_SCORES 2
#define EPI_AV     3
#define EPI_GELU   4
#define EPI_RESID  5

// ---------------------------------------------------------------------------
// Generic bf16 MFMA GEMM: C[M,N] = A[M,K] * B[N,K]^T, fp32 accumulate.
// Block: 256 threads = 4 waves, tile 128x128, BK=32, one 16x16x32 MFMA per
// fragment pair per K-step. Rows clamped (edge tiles), stores masked.
// ---------------------------------------------------------------------------
template<int EPI>
__global__ __launch_bounds__(256)
void gemm_bt(const __hip_bfloat16* __restrict__ Ag,
             const __hip_bfloat16* __restrict__ Bg,
             const int M, const int N, const int K,
             const int lda, const int ldb,
             const long sA, const long sB,
             void* __restrict__ outv,
             const float* __restrict__ bias,
             const float* __restrict__ bias2,
             const int ldo, const float p1)
{
    __shared__ unsigned short As[128][32];
    __shared__ unsigned short Bs[128][32];
    const int tid  = threadIdx.x;
    const int lane = tid & 63;
    const int wave = tid >> 6;
    const int wm = (wave & 1) << 6;   // wave m-offset within tile
    const int wn = (wave >> 1) << 6;  // wave n-offset within tile
    const int m0 = blockIdx.y * 128;
    const int n0 = blockIdx.x * 128;
    const int z  = blockIdx.z;
    const __hip_bfloat16* A = Ag + (size_t)z * sA;
    const __hip_bfloat16* B = Bg + (size_t)z * sB;

    f32x4 acc[4][4] = {};

    const int fr = lane & 15;          // fragment row (m for A, n for B)
    const int q8 = (lane >> 4) << 3;   // k base within BK
    const int rr = tid >> 2;           // staging row 0..63
    const int kc = (tid & 3) << 3;     // staging k-chunk (8 bf16)

    for (int k0 = 0; k0 < K; k0 += 32) {
        #pragma unroll
        for (int i = 0; i < 2; ++i) {
            const int r = rr + (i << 6);
            int ra = m0 + r; ra = (ra < M) ? ra : (M - 1);
            int rb = n0 + r; rb = (rb < N) ? rb : (N - 1);
            const uint4 va = *(const uint4*)(A + (size_t)ra * lda + (k0 + kc));
            const uint4 vb = *(const uint4*)(B + (size_t)rb * ldb + (k0 + kc));
            *(uint4*)(&As[r][kc]) = va;
            *(uint4*)(&Bs[r][kc]) = vb;
        }
        __syncthreads();
        bf16x8 af[4], bfr[4];
        #pragma unroll
        for (int mi = 0; mi < 4; ++mi) {
            af[mi] = *(const bf16x8*)(&As[wm + (mi << 4) + fr][q8]);
        }
        #pragma unroll
        for (int ni = 0; ni < 4; ++ni) {
            bfr[ni] = *(const bf16x8*)(&Bs[wn + (ni << 4) + fr][q8]);
        }
        #pragma unroll
        for (int mi = 0; mi < 4; ++mi) {
            #pragma unroll
            for (int ni = 0; ni < 4; ++ni) {
                acc[mi][ni] = __builtin_amdgcn_mfma_f32_16x16x32_bf16(
                    af[mi], bfr[ni], acc[mi][ni], 0, 0, 0);
            }
        }
        __syncthreads();
    }

    // Epilogue. C/D layout: col n = lane&15, row m = (lane>>4)*4 + r.
    const int q4 = (lane >> 4) << 2;
    #pragma unroll
    for (int mi = 0; mi < 4; ++mi) {
        #pragma unroll
        for (int ni = 0; ni < 4; ++ni) {
            #pragma unroll
            for (int r = 0; r < 4; ++r) {
                const int m = m0 + wm + (mi << 4) + q4 + r;
                const int n = n0 + wn + (ni << 4) + fr;
                if (m < M && n < N) {
                    const float v = acc[mi][ni][r];
                    if (EPI == EPI_PATCH) {
                        // h row = b*197 + 1 + p ; pos row = 1 + p
                        float* h = (float*)outv;
                        const int b = m / 196;
                        const int pp = m - b * 196;
                        h[(size_t)(m + b + 1) * 768 + n] =
                            v + bias[n] + bias2[(size_t)(1 + pp) * 768 + n];
                    } else if (EPI == EPI_QKV) {
                        __hip_bfloat16* o = (__hip_bfloat16*)outv;
                        const int b = m / 197, s = m - b * 197;
                        const int hh = n / 768, kq = n - hh * 768;
                        o[((size_t)((b * 12 + hh) * 197 + s)) * 768 + kq] =
                            __float2bfloat16(v + bias[n]);
                    } else if (EPI == EPI_SCORES) {
                        float* o = (float*)outv + (size_t)z * 38809;
                        o[(size_t)m * 197 + n] = v * p1;
                    } else if (EPI == EPI_AV) {
                        __hip_bfloat16* o = (__hip_bfloat16*)outv;
                        const int b = z / 12, hh = z - b * 12;
                        o[(size_t)b * 197 * 9216 + (size_t)m * 9216 + hh * 768 + n] =
                            __float2bfloat16(v);
                    } else if (EPI == EPI_GELU) {
                        __hip_bfloat16* o = (__hip_bfloat16*)outv;
                        const float t = v + bias[n];
                        o[(size_t)m * ldo + n] =
                            __float2bfloat16(0.5f * t * (1.0f + erff(t * 0.70710678118654752f)));
                    } else if (EPI == EPI_RESID) {
                        float* h = (float*)outv;
                        h[(size_t)m * 768 + n] += v + bias[n];
                    }
                }
            }
        }
    }
}

// ---------------------------------------------------------------------------
// LayerNorm (shared stats, no affine — affine folded into following weights)
// ---------------------------------------------------------------------------
__global__ __launch_bounds__(256)
void ln_rows(const float* __restrict__ h, __hip_bfloat16* __restrict__ xn)
{
    const int r = blockIdx.x;
    const float* x = h + (size_t)r * 768;
    float v[3]; float s = 0.f, sq = 0.f;
    #pragma unroll
    for (int i = 0; i < 3; ++i) {
        v[i] = x[threadIdx.x + i * 256];
        s += v[i]; sq += v[i] * v[i];
    }
    __shared__ float sb[8];
    #pragma unroll
    for (int off = 32; off; off >>= 1) {
        s += __shfl_down(s, off); sq += __shfl_down(sq, off);
    }
    const int w = threadIdx.x >> 6;
    if ((threadIdx.x & 63) == 0) { sb[w] = s; sb[4 + w] = sq; }
    __syncthreads();
    s = sb[0] + sb[1] + sb[2] + sb[3];
    sq = sb[4] + sb[5] + sb[6] + sb[7];
    const float mu = s * (1.f / 768.f);
    const float var = sq * (1.f / 768.f) - mu * mu;
    const float rstd = rsqrtf(var + 1e-5f);
    __hip_bfloat16* o = xn + (size_t)r * 768;
    #pragma unroll
    for (int i = 0; i < 3; ++i) {
        o[threadIdx.x + i * 256] = __float2bfloat16((v[i] - mu) * rstd);
    }
}

// ---------------------------------------------------------------------------
// Softmax over the QUERY axis (per fixed key column). Thread t owns column k.
// Writes probs [q][k] bf16, zero-padded in k to 224.
// ---------------------------------------------------------------------------
__global__ __launch_bounds__(256)
void softmax_q(const float* __restrict__ scores, __hip_bfloat16* __restrict__ probs)
{
    const int z = blockIdx.x;
    const float* sc = scores + (size_t)z * 38809;
    __hip_bfloat16* pr = probs + (size_t)z * 197 * 224;
    const int k = threadIdx.x;
    if (k >= 224) return;
    if (k < 197) {
        float mx = -1e30f;
        for (int q = 0; q < 197; ++q) mx = fmaxf(mx, sc[(size_t)q * 197 + k]);
        float sum = 0.f;
        for (int q = 0; q < 197; ++q) sum += expf(sc[(size_t)q * 197 + k] - mx);
        const float inv = 1.f / sum;
        for (int q = 0; q < 197; ++q) {
            pr[(size_t)q * 224 + k] =
                __float2bfloat16(expf(sc[(size_t)q * 197 + k] - mx) * inv);
        }
    } else {
        const __hip_bfloat16 zz = __float2bfloat16(0.f);
        for (int q = 0; q < 197; ++q) pr[(size_t)q * 224 + k] = zz;
    }
}

// ---------------------------------------------------------------------------
// Tiled transpose + fp32->bf16 convert, with optional row gain (LN gamma fold)
// and optional bias reduce (bvec @ W accumulated into bias_out via atomics).
// src [R][C] fp32 -> dst [C][R] bf16.  R, C multiples of 32.
// ---------------------------------------------------------------------------
__device__ __forceinline__
void tconv_body(const float* __restrict__ src, __hip_bfloat16* __restrict__ dst,
                const int R, const int C,
                const float* __restrict__ gain, const float* __restrict__ bvec,
                float* __restrict__ bias_out, const int r0, const int c0)
{
    __shared__ float tile[32][33];
    __shared__ float pb[8][32];
    const int tx = threadIdx.x & 31, ty = threadIdx.x >> 5;
    float bacc = 0.f;
    #pragma unroll
    for (int i = 0; i < 4; ++i) {
        const int r = r0 + ty + i * 8;
        const float w = src[(size_t)r * C + c0 + tx];
        tile[ty + i * 8][tx] = w * (gain ? gain[r] : 1.f);
        if (bvec) bacc += bvec[r] * w;
    }
    if (bias_out) pb[ty][tx] = bacc;
    __syncthreads();
    #pragma unroll
    for (int i = 0; i < 4; ++i) {
        const int c = c0 + ty + i * 8;
        dst[(size_t)c * R + r0 + tx] = __float2bfloat16(tile[tx][ty + i * 8]);
    }
    if (bias_out && ty == 0) {
        float sum = 0.f;
        #pragma unroll
        for (int j = 0; j < 8; ++j) sum += pb[j][tx];
        atomicAdd(&bias_out[c0 + tx], sum);
    }
}

__global__ __launch_bounds__(256)
void tconv_plain(const float* __restrict__ src, __hip_bfloat16* __restrict__ dst,
                 const int R, const int C, const float* __restrict__ gain,
                 const float* __restrict__ bvec, float* __restrict__ bias_out)
{
    tconv_body(src, dst, R, C, gain, bvec, bias_out, blockIdx.y * 32, blockIdx.x * 32);
}

__global__ __launch_bounds__(256)
void tconv_qkv(const float* __restrict__ Wq, const float* __restrict__ Wk,
               const float* __restrict__ Wv, const float* __restrict__ g1,
               const float* __restrict__ b1, __hip_bfloat16* __restrict__ dst,
               float* __restrict__ bias_out, const int l)
{
    const int zz = blockIdx.z;            // 0..35
    const int proj = zz / 12, hh = zz - proj * 12;
    const float* W = (proj == 0) ? Wq : ((proj == 1) ? Wk : Wv);
    const float* src = W + (size_t)(l * 12 + hh) * 768 * 768;
    const float* g = g1 + (size_t)(l * 12 + hh) * 768;
    const float* bv = b1 + (size_t)(l * 12 + hh) * 768;
    __hip_bfloat16* d = dst + ((size_t)proj * 9216 + (size_t)hh * 768) * 768;
    float* bo = bias_out + proj * 9216 + hh * 768;
    tconv_body(src, d, 768, 768, g, bv, bo, blockIdx.y * 32, blockIdx.x * 32);
}

// v [197][768] bf16 -> v^T [768][224] bf16 (zero-padded cols 197..223)
__global__ __launch_bounds__(256)
void vtrans(const __hip_bfloat16* __restrict__ v, __hip_bfloat16* __restrict__ vt)
{
    const int z = blockIdx.z;
    const __hip_bfloat16* src = v + (size_t)z * 197 * 768;
    __hip_bfloat16* dst = vt + (size_t)z * 768 * 224;
    __shared__ __hip_bfloat16 tile[32][33];
    const int tx = threadIdx.x & 31, ty = threadIdx.x >> 5;
    const int s0 = blockIdx.y * 32, d0 = blockIdx.x * 32;
    #pragma unroll
    for (int i = 0; i < 4; ++i) {
        const int s = s0 + ty + i * 8;
        tile[ty + i * 8][tx] = (s < 197) ? src[(size_t)s * 768 + d0 + tx]
                                         : __float2bfloat16(0.f);
    }
    __syncthreads();
    #pragma unroll
    for (int i = 0; i < 4; ++i) {
        const int d = d0 + ty + i * 8;
        dst[(size_t)d * 224 + s0 + tx] = tile[tx][ty + i * 8];
    }
}

// im2col for the stride-16 patch conv: A[(b,ph*14+pw)][(c*256+p*16+q)]
__global__ void im2col_patch(const float* __restrict__ x, __hip_bfloat16* __restrict__ Ap)
{
    const int idx = blockIdx.x * 256 + threadIdx.x;
    if (idx >= 3136 * 768) return;
    const int m = idx / 768, kk = idx - m * 768;
    const int b = m / 196, pidx = m - b * 196;
    const int ph = pidx / 14, pw = pidx - ph * 14;
    const int c = kk >> 8, rrr = kk & 255;
    const int p = rrr >> 4, q = rrr & 15;
    Ap[idx] = __float2bfloat16(
        x[(((size_t)b * 3 + c) * 224 + ph * 16 + p) * 224 + pw * 16 + q]);
}

__global__ void conv_ew(const float* __restrict__ src, __hip_bfloat16* __restrict__ dst, const int n)
{
    const int i = blockIdx.x * 256 + threadIdx.x;
    if (i < n) dst[i] = __float2bfloat16(src[i]);
}

__global__ void cls_pos(const float* __restrict__ cls, const float* __restrict__ pos,
                        float* __restrict__ h)
{
    const int i = blockIdx.x * 256 + threadIdx.x;
    if (i < 16 * 768) {
        const int b = i / 768, d = i - b * 768;
        h[(size_t)b * 197 * 768 + d] = cls[d] + pos[d];
    }
}

__global__ void binit_qkv(const float* __restrict__ bq, const float* __restrict__ bk,
                          const float* __restrict__ bv, float* __restrict__ bias, const int l)
{
    const int n = blockIdx.x * 256 + threadIdx.x;
    if (n < 3 * 9216) {
        const int proj = n / 9216, rem = n - proj * 9216;
        const int hh = rem / 768, kq = rem - hh * 768;
        const float* src = (proj == 0) ? bq : ((proj == 1) ? bk : bv);
        bias[n] = src[(size_t)(l * 12 + hh) * 768 + kq];
    }
}

__global__ void binit_vec(const float* __restrict__ src, float* __restrict__ dst, const int n)
{
    const int i = blockIdx.x * 256 + threadIdx.x;
    if (i < n) dst[i] = src[i];
}

// final: LN(h[:,0]) * lnf_g + lnf_b, then @ Wc[768,4] + bc
__global__ __launch_bounds__(256)
void final_head(const float* __restrict__ h, const float* __restrict__ lnfg,
                const float* __restrict__ lnfb, const float* __restrict__ Wc,
                const float* __restrict__ bc, float* __restrict__ out)
{
    const int b = blockIdx.x;
    const float* x = h + (size_t)b * 197 * 768;
    float v[3]; float s = 0.f, sq = 0.f;
    #pragma unroll
    for (int i = 0; i < 3; ++i) {
        v[i] = x[threadIdx.x + i * 256];
        s += v[i]; sq += v[i] * v[i];
    }
    __shared__ float sb[8];
    #pragma unroll
    for (int off = 32; off; off >>= 1) {
        s += __shfl_down(s, off); sq += __shfl_down(sq, off);
    }
    const int w = threadIdx.x >> 6;
    if ((threadIdx.x & 63) == 0) { sb[w] = s; sb[4 + w] = sq; }
    __syncthreads();
    s = sb[0] + sb[1] + sb[2] + sb[3];
    sq = sb[4] + sb[5] + sb[6] + sb[7];
    const float mu = s * (1.f / 768.f);
    const float var = sq * (1.f / 768.f) - mu * mu;
    const float rstd = rsqrtf(var + 1e-5f);
    float pacc[4] = {0.f, 0.f, 0.f, 0.f};
    #pragma unroll
    for (int i = 0; i < 3; ++i) {
        const int d = threadIdx.x + i * 256;
        const float c = (v[i] - mu) * rstd * lnfg[d] + lnfb[d];
        #pragma unroll
        for (int n = 0; n < 4; ++n) pacc[n] += c * Wc[d * 4 + n];
    }
    __shared__ float rb[4][4];
    #pragma unroll
    for (int off = 32; off; off >>= 1) {
        #pragma unroll
        for (int n = 0; n < 4; ++n) pacc[n] += __shfl_down(pacc[n], off);
    }
    if ((threadIdx.x & 63) == 0) {
        #pragma unroll
        for (int n = 0; n < 4; ++n) rb[w][n] = pacc[n];
    }
    __syncthreads();
    if (threadIdx.x < 4) {
        out[b * 4 + threadIdx.x] =
            rb[0][threadIdx.x] + rb[1][threadIdx.x] + rb[2][threadIdx.x] +
            rb[3][threadIdx.x] + bc[threadIdx.x];
    }
}

// ---------------------------------------------------------------------------
extern "C" void kernel_launch(void* const* d_in, const int* in_sizes, int n_in,
                              void* d_out, int out_size, void* d_ws, size_t ws_size,
                              hipStream_t stream)
{
    const float* x    = (const float*)d_in[0];
    const float* Wp   = (const float*)d_in[1];
    const float* bp   = (const float*)d_in[2];
    const float* cls  = (const float*)d_in[3];
    const float* pos  = (const float*)d_in[4];
    const float* g1   = (const float*)d_in[5];
    const float* b1v  = (const float*)d_in[6];
    const float* Wq   = (const float*)d_in[7];
    const float* bq   = (const float*)d_in[8];
    const float* Wk   = (const float*)d_in[9];
    const float* bk   = (const float*)d_in[10];
    const float* Wv   = (const float*)d_in[11];
    const float* bv   = (const float*)d_in[12];
    const float* Wo   = (const float*)d_in[13];
    const float* bo   = (const float*)d_in[14];
    const float* g2   = (const float*)d_in[15];
    const float* b2v  = (const float*)d_in[16];
    const float* W1   = (const float*)d_in[17];
    const float* bb1  = (const float*)d_in[18];
    const float* W2   = (const float*)d_in[19];
    const float* bb2  = (const float*)d_in[20];
    const float* lnfg = (const float*)d_in[21];
    const float* lnfb = (const float*)d_in[22];
    const float* Wc   = (const float*)d_in[23];
    const float* bc   = (const float*)d_in[24];
    float* out = (float*)d_out;

    char* p = (char*)d_ws;
    auto alloc = [&](size_t bytes) {
        char* r = p; p += (bytes + 255) & ~(size_t)255; return r;
    };
    float*          h       = (float*)         alloc((size_t)3152 * 768 * 4);
    __hip_bfloat16* xn      = (__hip_bfloat16*)alloc((size_t)3152 * 768 * 2);
    __hip_bfloat16* Ap      = (__hip_bfloat16*)alloc((size_t)3136 * 768 * 2);
    __hip_bfloat16* Wpb     = (__hip_bfloat16*)alloc((size_t)768 * 768 * 2);
    __hip_bfloat16* Wqkvl   = (__hip_bfloat16*)alloc((size_t)3 * 9216 * 768 * 2);
    float*          biasqkv = (float*)         alloc((size_t)3 * 9216 * 4);
    __hip_bfloat16* Wol     = (__hip_bfloat16*)alloc((size_t)768 * 9216 * 2);
    __hip_bfloat16* W1l     = (__hip_bfloat16*)alloc((size_t)3072 * 768 * 2);
    float*          bias1   = (float*)         alloc((size_t)3072 * 4);
    __hip_bfloat16* W2l     = (__hip_bfloat16*)alloc((size_t)768 * 3072 * 2);
    __hip_bfloat16* qb      = (__hip_bfloat16*)alloc((size_t)192 * 197 * 768 * 2);
    __hip_bfloat16* kb      = (__hip_bfloat16*)alloc((size_t)192 * 197 * 768 * 2);
    __hip_bfloat16* vb      = (__hip_bfloat16*)alloc((size_t)192 * 197 * 768 * 2);
    __hip_bfloat16* vt      = (__hip_bfloat16*)alloc((size_t)192 * 768 * 224 * 2);
    float*          sc      = (float*)         alloc((size_t)192 * 197 * 197 * 4);
    __hip_bfloat16* pr      = (__hip_bfloat16*)alloc((size_t)192 * 197 * 224 * 2);
    __hip_bfloat16* cat     = (__hip_bfloat16*)alloc((size_t)3152 * 9216 * 2);
    __hip_bfloat16* hid     = (__hip_bfloat16*)alloc((size_t)3152 * 3072 * 2);
    (void)in_sizes; (void)n_in; (void)out_size; (void)ws_size;

    // ---- patch embed ----
    conv_ew<<<(768 * 768 + 255) / 256, 256, 0, stream>>>(Wp, Wpb, 768 * 768);
    im2col_patch<<<(3136 * 768 + 255) / 256, 256, 0, stream>>>(x, Ap);
    cls_pos<<<(16 * 768 + 255) / 256, 256, 0, stream>>>(cls, pos, h);
    gemm_bt<EPI_PATCH><<<dim3(6, 25, 1), 256, 0, stream>>>(
        Ap, Wpb, 3136, 768, 768, 768, 768, 0, 0, h, bp, pos, 768, 0.f);

    const float sinv = 0.036084391824351615f; // 1/sqrt(768)

    for (int l = 0; l < 4; ++l) {
        // weight preprocessing (LN affine folded in)
        binit_qkv<<<(27648 + 255) / 256, 256, 0, stream>>>(bq, bk, bv, biasqkv, l);
        tconv_qkv<<<dim3(24, 24, 36), 256, 0, stream>>>(Wq, Wk, Wv, g1, b1v, Wqkvl, biasqkv, l);
        tconv_plain<<<dim3(24, 288, 1), 256, 0, stream>>>(
            Wo + (size_t)l * 9216 * 768, Wol, 9216, 768, nullptr, nullptr, nullptr);
        binit_vec<<<(3072 + 255) / 256, 256, 0, stream>>>(bb1 + (size_t)l * 3072, bias1, 3072);
        tconv_plain<<<dim3(96, 24, 1), 256, 0, stream>>>(
            W1 + (size_t)l * 768 * 3072, W1l, 768, 3072, g2 + l * 768, b2v + l * 768, bias1);
        tconv_plain<<<dim3(24, 96, 1), 256, 0, stream>>>(
            W2 + (size_t)l * 3072 * 768, W2l, 3072, 768, nullptr, nullptr, nullptr);

        // attention
        ln_rows<<<3152, 256, 0, stream>>>(h, xn);
        gemm_bt<EPI_QKV><<<dim3(72, 25, 1), 256, 0, stream>>>(
            xn, Wqkvl, 3152, 9216, 768, 768, 768, 0, 0, qb, biasqkv, nullptr, 0, 0.f);
        gemm_bt<EPI_QKV><<<dim3(72, 25, 1), 256, 0, stream>>>(
            xn, Wqkvl + (size_t)9216 * 768, 3152, 9216, 768, 768, 768, 0, 0,
            kb, biasqkv + 9216, nullptr, 0, 0.f);
        gemm_bt<EPI_QKV><<<dim3(72, 25, 1), 256, 0, stream>>>(
            xn, Wqkvl + (size_t)2 * 9216 * 768, 3152, 9216, 768, 768, 768, 0, 0,
            vb, biasqkv + 2 * 9216, nullptr, 0, 0.f);
        vtrans<<<dim3(24, 7, 192), 256, 0, stream>>>(vb, vt);
        gemm_bt<EPI_SCORES><<<dim3(2, 2, 192), 256, 0, stream>>>(
            qb, kb, 197, 197, 768, 768, 768, (long)197 * 768, (long)197 * 768,
            sc, nullptr, nullptr, 197, sinv);
        softmax_q<<<192, 256, 0, stream>>>(sc, pr);
        gemm_bt<EPI_AV><<<dim3(6, 2, 192), 256, 0, stream>>>(
            pr, vt, 197, 768, 224, 224, 224, (long)197 * 224, (long)768 * 224,
            cat, nullptr, nullptr, 0, 0.f);
        gemm_bt<EPI_RESID><<<dim3(6, 25, 1), 256, 0, stream>>>(
            cat, Wol, 3152, 768, 9216, 9216, 9216, 0, 0, h, bo + l * 768, nullptr, 768, 0.f);

        // MLP
        ln_rows<<<3152, 256, 0, stream>>>(h, xn);
        gemm_bt<EPI_GELU><<<dim3(24, 25, 1), 256, 0, stream>>>(
            xn, W1l, 3152, 3072, 768, 768, 768, 0, 0, hid, bias1, nullptr, 3072, 0.f);
        gemm_bt<EPI_RESID><<<dim3(6, 25, 1), 256, 0, stream>>>(
            hid, W2l, 3152, 768, 3072, 3072, 3072, 0, 0, h, bb2 + l * 768, nullptr, 768, 0.f);
    }

    final_head<<<16, 256, 0, stream>>>(h, lnfg, lnfb, Wc, bc, out);
}

// Round 2
// 3661.424 us; speedup vs baseline: 1.1891x; 1.1891x over previous
//
#include <hip/hip_runtime.h>
#include <hip/hip_bf16.h>
#include <math.h>

typedef float f32x4 __attribute__((ext_vector_type(4)));
typedef __bf16 bf16x8 __attribute__((ext_vector_type(8)));

#define EPI_PATCH  0
#define EPI_QKV    1
#define EPI_SCORES 2
#define EPI_AV     3
#define EPI_GELU   4
#define EPI_RESID  5

// async 16B global->LDS (wave-uniform LDS base + lane*16)
__device__ __forceinline__ void gld16(const void* g, void* l) {
    __builtin_amdgcn_global_load_lds(
        (const __attribute__((address_space(1))) unsigned int*)g,
        (__attribute__((address_space(3))) unsigned int*)l, 16, 0, 0);
}

// ---------------------------------------------------------------------------
// bf16 MFMA GEMM: C[M,N] = A[M,K] * B[N,K]^T, fp32 accumulate.
// 256 thr = 4 waves, tile 128x128, BK=32. global_load_lds staging (16B),
// XOR k-chunk swizzle (applied on fetch side) to kill b128 bank conflicts.
// SPLIT: blockIdx.z = K-chunk index (size Kc), epilogue atomicAdd.
// ---------------------------------------------------------------------------
template<int EPI, bool SPLIT>
__global__ __launch_bounds__(256)
void gemm_bt(const __hip_bfloat16* __restrict__ Ag,
             const __hip_bfloat16* __restrict__ Bg,
             const int M, const int N, const int K,
             const int lda, const int ldb,
             const long sA, const long sB,
             void* __restrict__ outv,
             const float* __restrict__ bias,
             const int ldo, const float p1, const int Kc)
{
    __shared__ unsigned short As[128][32];
    __shared__ unsigned short Bs[128][32];
    const int tid  = threadIdx.x;
    const int lane = tid & 63;
    const int wave = tid >> 6;
    const int wm = (wave & 1) << 6;
    const int wn = (wave >> 1) << 6;
    const int m0 = blockIdx.y * 128;
    const int n0 = blockIdx.x * 128;
    const int z  = blockIdx.z;
    const __hip_bfloat16* A = Ag + (size_t)z * sA;
    const __hip_bfloat16* B = Bg + (size_t)z * sB;

    f32x4 acc[4][4] = {};

    const int fr  = lane & 15;                                // fragment row
    const int rr  = tid >> 2;                                 // staging row 0..63
    const int ksw = (((tid & 3) ^ ((tid >> 3) & 3)) << 3);    // swizzled k-chunk (elems)
    const int colX = (((lane >> 4) ^ ((fr >> 1) & 3)) << 3);  // frag col after swizzle

    int kBeg = 0, kEnd = K;
    if (SPLIT) { kBeg = z * Kc; kEnd = (kBeg + Kc < K) ? (kBeg + Kc) : K; }

    for (int k0 = kBeg; k0 < kEnd; k0 += 32) {
        #pragma unroll
        for (int i = 0; i < 2; ++i) {
            int ra = m0 + rr + (i << 6); ra = (ra < M) ? ra : (M - 1);
            int rb = n0 + rr + (i << 6); rb = (rb < N) ? rb : (N - 1);
            gld16(A + (size_t)ra * lda + (k0 + ksw), &As[(wave << 4) + (i << 6)][0]);
            gld16(B + (size_t)rb * ldb + (k0 + ksw), &Bs[(wave << 4) + (i << 6)][0]);
        }
        __syncthreads();
        bf16x8 af[4], bfr[4];
        #pragma unroll
        for (int mi = 0; mi < 4; ++mi)
            af[mi] = *(const bf16x8*)(&As[wm + (mi << 4) + fr][colX]);
        #pragma unroll
        for (int ni = 0; ni < 4; ++ni)
            bfr[ni] = *(const bf16x8*)(&Bs[wn + (ni << 4) + fr][colX]);
        #pragma unroll
        for (int mi = 0; mi < 4; ++mi)
            #pragma unroll
            for (int ni = 0; ni < 4; ++ni)
                acc[mi][ni] = __builtin_amdgcn_mfma_f32_16x16x32_bf16(
                    af[mi], bfr[ni], acc[mi][ni], 0, 0, 0);
        __syncthreads();
    }

    // Epilogue. C/D layout: col n = lane&15, row m = (lane>>4)*4 + r.
    const int q4 = (lane >> 4) << 2;
    #pragma unroll
    for (int mi = 0; mi < 4; ++mi) {
        #pragma unroll
        for (int ni = 0; ni < 4; ++ni) {
            #pragma unroll
            for (int r = 0; r < 4; ++r) {
                const int m = m0 + wm + (mi << 4) + q4 + r;
                const int n = n0 + wn + (ni << 4) + fr;
                if (m < M && n < N) {
                    const float v = acc[mi][ni][r];
                    if (EPI == EPI_PATCH) {
                        // bias+pos already in h via hinit; atomic split-K add
                        float* h = (float*)outv;
                        const int b = m / 196;
                        atomicAdd(&h[(size_t)(m + b + 1) * 768 + n], v);
                    } else if (EPI == EPI_QKV) {
                        // merged q/k/v: n in [0, 27648)
                        __hip_bfloat16* o = (__hip_bfloat16*)outv;
                        const int b = m / 197, s = m - b * 197;
                        const int proj = n / 9216, rem = n - proj * 9216;
                        const int hh = rem / 768, kq = rem - hh * 768;
                        o[(size_t)proj * 29048832 +
                          ((size_t)((b * 12 + hh) * 197 + s)) * 768 + kq] =
                            __float2bfloat16(v + bias[n]);
                    } else if (EPI == EPI_SCORES) {
                        float* o = (float*)outv + (size_t)z * 38809;
                        o[(size_t)m * 197 + n] = v * p1;
                    } else if (EPI == EPI_AV) {
                        __hip_bfloat16* o = (__hip_bfloat16*)outv;
                        const int b = z / 12, hh = z - b * 12;
                        o[(size_t)b * 197 * 9216 + (size_t)m * 9216 + hh * 768 + n] =
                            __float2bfloat16(v);
                    } else if (EPI == EPI_GELU) {
                        __hip_bfloat16* o = (__hip_bfloat16*)outv;
                        const float t = v + bias[n];
                        o[(size_t)m * ldo + n] =
                            __float2bfloat16(0.5f * t * (1.0f + erff(t * 0.70710678118654752f)));
                    } else if (EPI == EPI_RESID) {
                        float* h = (float*)outv;
                        if (SPLIT) {
                            atomicAdd(&h[(size_t)m * 768 + n],
                                      v + ((z == 0) ? bias[n] : 0.f));
                        } else {
                            h[(size_t)m * 768 + n] += v + bias[n];
                        }
                    }
                }
            }
        }
    }
}

// ---------------------------------------------------------------------------
// LayerNorm (shared stats, no affine — affine folded into following weights)
// ---------------------------------------------------------------------------
__global__ __launch_bounds__(256)
void ln_rows(const float* __restrict__ h, __hip_bfloat16* __restrict__ xn)
{
    const int r = blockIdx.x;
    const float* x = h + (size_t)r * 768;
    float v[3]; float s = 0.f, sq = 0.f;
    #pragma unroll
    for (int i = 0; i < 3; ++i) {
        v[i] = x[threadIdx.x + i * 256];
        s += v[i]; sq += v[i] * v[i];
    }
    __shared__ float sb[8];
    #pragma unroll
    for (int off = 32; off; off >>= 1) {
        s += __shfl_down(s, off); sq += __shfl_down(sq, off);
    }
    const int w = threadIdx.x >> 6;
    if ((threadIdx.x & 63) == 0) { sb[w] = s; sb[4 + w] = sq; }
    __syncthreads();
    s = sb[0] + sb[1] + sb[2] + sb[3];
    sq = sb[4] + sb[5] + sb[6] + sb[7];
    const float mu = s * (1.f / 768.f);
    const float var = sq * (1.f / 768.f) - mu * mu;
    const float rstd = rsqrtf(var + 1e-5f);
    __hip_bfloat16* o = xn + (size_t)r * 768;
    #pragma unroll
    for (int i = 0; i < 3; ++i)
        o[threadIdx.x + i * 256] = __float2bfloat16((v[i] - mu) * rstd);
}

// ---------------------------------------------------------------------------
// Softmax over the QUERY axis. Thread t owns key column k; coalesced reads.
// ---------------------------------------------------------------------------
__global__ __launch_bounds__(256)
void softmax_q(const float* __restrict__ scores, __hip_bfloat16* __restrict__ probs)
{
    const int z = blockIdx.x;
    const float* sc = scores + (size_t)z * 38809;
    __hip_bfloat16* pr = probs + (size_t)z * 197 * 224;
    const int k = threadIdx.x;
    if (k >= 224) return;
    if (k < 197) {
        float mx = -1e30f;
        for (int q = 0; q < 197; ++q) mx = fmaxf(mx, sc[(size_t)q * 197 + k]);
        float sum = 0.f;
        for (int q = 0; q < 197; ++q) sum += expf(sc[(size_t)q * 197 + k] - mx);
        const float inv = 1.f / sum;
        for (int q = 0; q < 197; ++q)
            pr[(size_t)q * 224 + k] =
                __float2bfloat16(expf(sc[(size_t)q * 197 + k] - mx) * inv);
    } else {
        const __hip_bfloat16 zz = __float2bfloat16(0.f);
        for (int q = 0; q < 197; ++q) pr[(size_t)q * 224 + k] = zz;
    }
}

// ---------------------------------------------------------------------------
// Tiled transpose + fp32->bf16, optional row gain (LN gamma) + bias reduce.
// ---------------------------------------------------------------------------
__device__ __forceinline__
void tconv_body(const float* __restrict__ src, __hip_bfloat16* __restrict__ dst,
                const int R, const int C,
                const float* __restrict__ gain, const float* __restrict__ bvec,
                float* __restrict__ bias_out, const int r0, const int c0)
{
    __shared__ float tile[32][33];
    __shared__ float pb[8][32];
    const int tx = threadIdx.x & 31, ty = threadIdx.x >> 5;
    float bacc = 0.f;
    #pragma unroll
    for (int i = 0; i < 4; ++i) {
        const int r = r0 + ty + i * 8;
        const float w = src[(size_t)r * C + c0 + tx];
        tile[ty + i * 8][tx] = w * (gain ? gain[r] : 1.f);
        if (bvec) bacc += bvec[r] * w;
    }
    if (bias_out) pb[ty][tx] = bacc;
    __syncthreads();
    #pragma unroll
    for (int i = 0; i < 4; ++i) {
        const int c = c0 + ty + i * 8;
        dst[(size_t)c * R + r0 + tx] = __float2bfloat16(tile[tx][ty + i * 8]);
    }
    if (bias_out && ty == 0) {
        float sum = 0.f;
        #pragma unroll
        for (int j = 0; j < 8; ++j) sum += pb[j][tx];
        atomicAdd(&bias_out[c0 + tx], sum);
    }
}

__global__ __launch_bounds__(256)
void tconv_plain(const float* __restrict__ src, __hip_bfloat16* __restrict__ dst,
                 const int R, const int C, const float* __restrict__ gain,
                 const float* __restrict__ bvec, float* __restrict__ bias_out)
{
    tconv_body(src, dst, R, C, gain, bvec, bias_out, blockIdx.y * 32, blockIdx.x * 32);
}

__global__ __launch_bounds__(256)
void tconv_qkv(const float* __restrict__ Wq, const float* __restrict__ Wk,
               const float* __restrict__ Wv, const float* __restrict__ g1,
               const float* __restrict__ b1, __hip_bfloat16* __restrict__ dst,
               float* __restrict__ bias_out, const int l)
{
    const int zz = blockIdx.z;            // 0..35
    const int proj = zz / 12, hh = zz - proj * 12;
    const float* W = (proj == 0) ? Wq : ((proj == 1) ? Wk : Wv);
    const float* src = W + (size_t)(l * 12 + hh) * 768 * 768;
    const float* g = g1 + (size_t)(l * 12 + hh) * 768;
    const float* bv = b1 + (size_t)(l * 12 + hh) * 768;
    __hip_bfloat16* d = dst + ((size_t)proj * 9216 + (size_t)hh * 768) * 768;
    float* bo = bias_out + proj * 9216 + hh * 768;
    tconv_body(src, d, 768, 768, g, bv, bo, blockIdx.y * 32, blockIdx.x * 32);
}

// v [197][768] bf16 -> v^T [768][224] bf16 (zero-padded cols 197..223)
__global__ __launch_bounds__(256)
void vtrans(const __hip_bfloat16* __restrict__ v, __hip_bfloat16* __restrict__ vt)
{
    const int z = blockIdx.z;
    const __hip_bfloat16* src = v + (size_t)z * 197 * 768;
    __hip_bfloat16* dst = vt + (size_t)z * 768 * 224;
    __shared__ __hip_bfloat16 tile[32][33];
    const int tx = threadIdx.x & 31, ty = threadIdx.x >> 5;
    const int s0 = blockIdx.y * 32, d0 = blockIdx.x * 32;
    #pragma unroll
    for (int i = 0; i < 4; ++i) {
        const int s = s0 + ty + i * 8;
        tile[ty + i * 8][tx] = (s < 197) ? src[(size_t)s * 768 + d0 + tx]
                                         : __float2bfloat16(0.f);
    }
    __syncthreads();
    #pragma unroll
    for (int i = 0; i < 4; ++i) {
        const int d = d0 + ty + i * 8;
        dst[(size_t)d * 224 + s0 + tx] = tile[tx][ty + i * 8];
    }
}

// im2col for the stride-16 patch conv
__global__ void im2col_patch(const float* __restrict__ x, __hip_bfloat16* __restrict__ Ap)
{
    const int idx = blockIdx.x * 256 + threadIdx.x;
    if (idx >= 3136 * 768) return;
    const int m = idx / 768, kk = idx - m * 768;
    const int b = m / 196, pidx = m - b * 196;
    const int ph = pidx / 14, pw = pidx - ph * 14;
    const int c = kk >> 8, rrr = kk & 255;
    const int p = rrr >> 4, q = rrr & 15;
    Ap[idx] = __float2bfloat16(
        x[(((size_t)b * 3 + c) * 224 + ph * 16 + p) * 224 + pw * 16 + q]);
}

__global__ void conv_ew(const float* __restrict__ src, __hip_bfloat16* __restrict__ dst, const int n)
{
    const int i = blockIdx.x * 256 + threadIdx.x;
    if (i < n) dst[i] = __float2bfloat16(src[i]);
}

// h init: row 0 = cls + pos[0]; patch rows = b_patch + pos[s]
__global__ void hinit(const float* __restrict__ cls, const float* __restrict__ pos,
                      const float* __restrict__ bp, float* __restrict__ h)
{
    const int i = blockIdx.x * 256 + threadIdx.x;
    if (i < 16 * 197 * 768) {
        const int rem = i % (197 * 768);
        const int s = rem / 768, d = rem - s * 768;
        h[i] = pos[rem] + ((s == 0) ? cls[d] : bp[d]);
    }
}

__global__ void binit_qkv(const float* __restrict__ bq, const float* __restrict__ bk,
                          const float* __restrict__ bv, float* __restrict__ bias, const int l)
{
    const int n = blockIdx.x * 256 + threadIdx.x;
    if (n < 3 * 9216) {
        const int proj = n / 9216, rem = n - proj * 9216;
        const int hh = rem / 768, kq = rem - hh * 768;
        const float* src = (proj == 0) ? bq : ((proj == 1) ? bk : bv);
        bias[n] = src[(size_t)(l * 12 + hh) * 768 + kq];
    }
}

__global__ void binit_vec(const float* __restrict__ src, float* __restrict__ dst, const int n)
{
    const int i = blockIdx.x * 256 + threadIdx.x;
    if (i < n) dst[i] = src[i];
}

// final: LN(h[:,0]) * lnf_g + lnf_b, then @ Wc[768,4] + bc
__global__ __launch_bounds__(256)
void final_head(const float* __restrict__ h, const float* __restrict__ lnfg,
                const float* __restrict__ lnfb, const float* __restrict__ Wc,
                const float* __restrict__ bc, float* __restrict__ out)
{
    const int b = blockIdx.x;
    const float* x = h + (size_t)b * 197 * 768;
    float v[3]; float s = 0.f, sq = 0.f;
    #pragma unroll
    for (int i = 0; i < 3; ++i) {
        v[i] = x[threadIdx.x + i * 256];
        s += v[i]; sq += v[i] * v[i];
    }
    __shared__ float sb[8];
    #pragma unroll
    for (int off = 32; off; off >>= 1) {
        s += __shfl_down(s, off); sq += __shfl_down(sq, off);
    }
    const int w = threadIdx.x >> 6;
    if ((threadIdx.x & 63) == 0) { sb[w] = s; sb[4 + w] = sq; }
    __syncthreads();
    s = sb[0] + sb[1] + sb[2] + sb[3];
    sq = sb[4] + sb[5] + sb[6] + sb[7];
    const float mu = s * (1.f / 768.f);
    const float var = sq * (1.f / 768.f) - mu * mu;
    const float rstd = rsqrtf(var + 1e-5f);
    float pacc[4] = {0.f, 0.f, 0.f, 0.f};
    #pragma unroll
    for (int i = 0; i < 3; ++i) {
        const int d = threadIdx.x + i * 256;
        const float c = (v[i] - mu) * rstd * lnfg[d] + lnfb[d];
        #pragma unroll
        for (int n = 0; n < 4; ++n) pacc[n] += c * Wc[d * 4 + n];
    }
    __shared__ float rb[4][4];
    #pragma unroll
    for (int off = 32; off; off >>= 1)
        #pragma unroll
        for (int n = 0; n < 4; ++n) pacc[n] += __shfl_down(pacc[n], off);
    if ((threadIdx.x & 63) == 0)
        #pragma unroll
        for (int n = 0; n < 4; ++n) rb[w][n] = pacc[n];
    __syncthreads();
    if (threadIdx.x < 4)
        out[b * 4 + threadIdx.x] =
            rb[0][threadIdx.x] + rb[1][threadIdx.x] + rb[2][threadIdx.x] +
            rb[3][threadIdx.x] + bc[threadIdx.x];
}

// ---------------------------------------------------------------------------
extern "C" void kernel_launch(void* const* d_in, const int* in_sizes, int n_in,
                              void* d_out, int out_size, void* d_ws, size_t ws_size,
                              hipStream_t stream)
{
    const float* x    = (const float*)d_in[0];
    const float* Wp   = (const float*)d_in[1];
    const float* bp   = (const float*)d_in[2];
    const float* cls  = (const float*)d_in[3];
    const float* pos  = (const float*)d_in[4];
    const float* g1   = (const float*)d_in[5];
    const float* b1v  = (const float*)d_in[6];
    const float* Wq   = (const float*)d_in[7];
    const float* bq   = (const float*)d_in[8];
    const float* Wk   = (const float*)d_in[9];
    const float* bk   = (const float*)d_in[10];
    const float* Wv   = (const float*)d_in[11];
    const float* bv   = (const float*)d_in[12];
    const float* Wo   = (const float*)d_in[13];
    const float* bo   = (const float*)d_in[14];
    const float* g2   = (const float*)d_in[15];
    const float* b2v  = (const float*)d_in[16];
    const float* W1   = (const float*)d_in[17];
    const float* bb1  = (const float*)d_in[18];
    const float* W2   = (const float*)d_in[19];
    const float* bb2  = (const float*)d_in[20];
    const float* lnfg = (const float*)d_in[21];
    const float* lnfb = (const float*)d_in[22];
    const float* Wc   = (const float*)d_in[23];
    const float* bc   = (const float*)d_in[24];
    float* out = (float*)d_out;

    char* p = (char*)d_ws;
    auto alloc = [&](size_t bytes) {
        char* r = p; p += (bytes + 255) & ~(size_t)255; return r;
    };
    float*          h       = (float*)         alloc((size_t)3152 * 768 * 4);
    __hip_bfloat16* xn      = (__hip_bfloat16*)alloc((size_t)3152 * 768 * 2);
    __hip_bfloat16* Ap      = (__hip_bfloat16*)alloc((size_t)3136 * 768 * 2);
    __hip_bfloat16* Wpb     = (__hip_bfloat16*)alloc((size_t)768 * 768 * 2);
    __hip_bfloat16* Wqkvl   = (__hip_bfloat16*)alloc((size_t)3 * 9216 * 768 * 2);
    float*          biasqkv = (float*)         alloc((size_t)3 * 9216 * 4);
    __hip_bfloat16* Wol     = (__hip_bfloat16*)alloc((size_t)768 * 9216 * 2);
    __hip_bfloat16* W1l     = (__hip_bfloat16*)alloc((size_t)3072 * 768 * 2);
    float*          bias1   = (float*)         alloc((size_t)3072 * 4);
    __hip_bfloat16* W2l     = (__hip_bfloat16*)alloc((size_t)768 * 3072 * 2);
    __hip_bfloat16* qb      = (__hip_bfloat16*)alloc((size_t)3 * 29048832 * 2); // q,k,v contiguous
    __hip_bfloat16* kb      = qb + (size_t)29048832;
    __hip_bfloat16* vb      = qb + (size_t)2 * 29048832;
    __hip_bfloat16* vt      = (__hip_bfloat16*)alloc((size_t)192 * 768 * 224 * 2);
    float*          sc      = (float*)         alloc((size_t)192 * 197 * 197 * 4);
    __hip_bfloat16* pr      = (__hip_bfloat16*)alloc((size_t)192 * 197 * 224 * 2);
    __hip_bfloat16* cat     = (__hip_bfloat16*)alloc((size_t)3152 * 9216 * 2);
    __hip_bfloat16* hid     = (__hip_bfloat16*)alloc((size_t)3152 * 3072 * 2);
    (void)in_sizes; (void)n_in; (void)out_size; (void)ws_size;

    // ---- patch embed ----
    conv_ew<<<(768 * 768 + 255) / 256, 256, 0, stream>>>(Wp, Wpb, 768 * 768);
    im2col_patch<<<(3136 * 768 + 255) / 256, 256, 0, stream>>>(x, Ap);
    hinit<<<(16 * 197 * 768 + 255) / 256, 256, 0, stream>>>(cls, pos, bp, h);
    gemm_bt<EPI_PATCH, true><<<dim3(6, 25, 4), 256, 0, stream>>>(
        Ap, Wpb, 3136, 768, 768, 768, 768, 0, 0, h, nullptr, 768, 0.f, 192);

    const float sinv = 0.036084391824351615f; // 1/sqrt(768)

    for (int l = 0; l < 4; ++l) {
        // weight preprocessing (LN affine folded in)
        binit_qkv<<<(27648 + 255) / 256, 256, 0, stream>>>(bq, bk, bv, biasqkv, l);
        tconv_qkv<<<dim3(24, 24, 36), 256, 0, stream>>>(Wq, Wk, Wv, g1, b1v, Wqkvl, biasqkv, l);
        tconv_plain<<<dim3(24, 288, 1), 256, 0, stream>>>(
            Wo + (size_t)l * 9216 * 768, Wol, 9216, 768, nullptr, nullptr, nullptr);
        binit_vec<<<(3072 + 255) / 256, 256, 0, stream>>>(bb1 + (size_t)l * 3072, bias1, 3072);
        tconv_plain<<<dim3(96, 24, 1), 256, 0, stream>>>(
            W1 + (size_t)l * 768 * 3072, W1l, 768, 3072, g2 + l * 768, b2v + l * 768, bias1);
        tconv_plain<<<dim3(24, 96, 1), 256, 0, stream>>>(
            W2 + (size_t)l * 3072 * 768, W2l, 3072, 768, nullptr, nullptr, nullptr);

        // attention
        ln_rows<<<3152, 256, 0, stream>>>(h, xn);
        gemm_bt<EPI_QKV, false><<<dim3(216, 25, 1), 256, 0, stream>>>(
            xn, Wqkvl, 3152, 27648, 768, 768, 768, 0, 0, qb, biasqkv, 0, 0.f, 0);
        vtrans<<<dim3(24, 7, 192), 256, 0, stream>>>(vb, vt);
        gemm_bt<EPI_SCORES, false><<<dim3(2, 2, 192), 256, 0, stream>>>(
            qb, kb, 197, 197, 768, 768, 768, (long)197 * 768, (long)197 * 768,
            sc, nullptr, 197, sinv, 0);
        softmax_q<<<192, 256, 0, stream>>>(sc, pr);
        gemm_bt<EPI_AV, false><<<dim3(6, 2, 192), 256, 0, stream>>>(
            pr, vt, 197, 768, 224, 224, 224, (long)197 * 224, (long)768 * 224,
            cat, nullptr, 0, 0.f, 0);
        gemm_bt<EPI_RESID, true><<<dim3(6, 25, 6), 256, 0, stream>>>(
            cat, Wol, 3152, 768, 9216, 9216, 9216, 0, 0, h, bo + l * 768, 768, 0.f, 1536);

        // MLP
        ln_rows<<<3152, 256, 0, stream>>>(h, xn);
        gemm_bt<EPI_GELU, false><<<dim3(24, 25, 1), 256, 0, stream>>>(
            xn, W1l, 3152, 3072, 768, 768, 768, 0, 0, hid, bias1, 3072, 0.f, 0);
        gemm_bt<EPI_RESID, true><<<dim3(6, 25, 4), 256, 0, stream>>>(
            hid, W2l, 3152, 768, 3072, 3072, 3072, 0, 0, h, bb2 + l * 768, 768, 0.f, 768);
    }

    final_head<<<16, 256, 0, stream>>>(h, lnfg, lnfb, Wc, bc, out);
}